// Round 3
// baseline (2930.147 us; speedup 1.0000x reference)
//
#include <hip/hip_runtime.h>
#include <hip/hip_bf16.h>

#define TT 20
#define BB 64
#define HH 512
#define VV 32000

typedef __bf16 bf16x8 __attribute__((ext_vector_type(8)));
typedef float f32x4 __attribute__((ext_vector_type(4)));

#define MFMA(a, b, c) __builtin_amdgcn_mfma_f32_16x16x32_bf16((a), (b), (c), 0, 0, 0)

// ---------------- elementwise helpers ----------------

__global__ __launch_bounds__(256) void f2bf_kernel(const float* __restrict__ in,
                                                   __hip_bfloat16* __restrict__ out, int n) {
    int i = blockIdx.x * 256 + threadIdx.x;
    if (i < n) out[i] = __float2bfloat16(in[i]);
}

// zero h state (fp32 + bf16) and the grid-barrier counter
__global__ __launch_bounds__(256) void init_kernel(float* __restrict__ hf,
                                                   __hip_bfloat16* __restrict__ hb, int n,
                                                   unsigned* __restrict__ barcnt) {
    int i = blockIdx.x * 256 + threadIdx.x;
    if (i < n) { hf[i] = 0.f; hb[i] = __float2bfloat16(0.f); }
    if (i == 0) *barcnt = 0u;
}

__global__ __launch_bounds__(256) void gather_emb_kernel(const float* __restrict__ tab,
                                                         const int* __restrict__ cap,
                                                         __hip_bfloat16* __restrict__ out) {
    int i = blockIdx.x * 256 + threadIdx.x;  // T*B*E
    int e = i & 511;
    int tb = i >> 9;          // t*64 + b
    int t = tb >> 6;
    int b = tb & 63;
    int tok = cap[b * TT + t];
    out[i] = __float2bfloat16(tab[(size_t)tok * 512 + e]);
}

// ---------------- fast 128x128-tile GEMM: C[M,N] = A[M,K] * B[N,K]^T (+bias) ----------------

__device__ inline void async16(const void* g, void* l) {
    __builtin_amdgcn_global_load_lds(
        (const __attribute__((address_space(1))) unsigned int*)g,
        (__attribute__((address_space(3))) unsigned int*)l, 16, 0, 0);
}

__global__ __launch_bounds__(256) void fastgemm_kernel(
    const __hip_bfloat16* __restrict__ A,
    const __hip_bfloat16* __restrict__ Bm,
    const float* __restrict__ bias,
    float* __restrict__ C,
    int K, int N)
{
    __shared__ __align__(16) __hip_bfloat16 lsA[128 * 32];
    __shared__ __align__(16) __hip_bfloat16 lsB[128 * 32];

    int m0 = blockIdx.x * 128, n0 = blockIdx.y * 128;
    int tid = threadIdx.x;
    int wave = tid >> 6, lane = tid & 63, row16 = lane & 15, quad = lane >> 4;
    int wm = wave & 1, wn = wave >> 1;

    int srow = tid >> 2;          // 0..63
    int scol = (tid & 3) * 8;     // bf16 elems
    const __hip_bfloat16* ga = A + (size_t)(m0 + srow) * K + scol;
    const __hip_bfloat16* gb = Bm + (size_t)(n0 + srow) * K + scol;
    __hip_bfloat16* la0 = &lsA[srow * 32 + scol];
    __hip_bfloat16* la1 = &lsA[(64 + srow) * 32 + scol];
    __hip_bfloat16* lb0 = &lsB[srow * 32 + scol];
    __hip_bfloat16* lb1 = &lsB[(64 + srow) * 32 + scol];

    f32x4 acc[4][4] = {};

    for (int kt = 0; kt < K; kt += 32) {
        async16(ga + kt, la0);
        async16(ga + kt + (size_t)64 * K, la1);
        async16(gb + kt, lb0);
        async16(gb + kt + (size_t)64 * K, lb1);
        __syncthreads();

        bf16x8 af[4], bfr[4];
#pragma unroll
        for (int i = 0; i < 4; ++i)
            af[i] = *(const bf16x8*)&lsA[(wm * 64 + i * 16 + row16) * 32 + quad * 8];
#pragma unroll
        for (int j = 0; j < 4; ++j)
            bfr[j] = *(const bf16x8*)&lsB[(wn * 64 + j * 16 + row16) * 32 + quad * 8];
#pragma unroll
        for (int i = 0; i < 4; ++i)
#pragma unroll
            for (int j = 0; j < 4; ++j)
                acc[i][j] = MFMA(af[i], bfr[j], acc[i][j]);
        __syncthreads();
    }

#pragma unroll
    for (int i = 0; i < 4; ++i)
#pragma unroll
        for (int j = 0; j < 4; ++j) {
            int col = n0 + wn * 64 + j * 16 + row16;
            float bv = bias ? bias[col] : 0.f;
#pragma unroll
            for (int r = 0; r < 4; ++r) {
                int row = m0 + wm * 64 + i * 16 + quad * 4 + r;
                C[(size_t)row * N + col] = acc[i][j][r] + bv;
            }
        }
}

// ---------------- recurrence kernel with manual grid barrier ----------------

__device__ inline float sigmf(float x) { return 1.f / (1.f + __expf(-x)); }

struct RecArgs {
    const __hip_bfloat16 *whh, *wih, *wq, *wo;
    const float *bih, *bhh, *bq, *bo;
    const float *GI0all;       // [20][64][1536]
    const float *KV;           // [4096][1024] (K cols 0:512, V 512:1024)
    float *hf;                 // [2][3][64][512]
    __hip_bfloat16 *hb;        // [2][3][64][512]
    float *qf;                 // [64][512]
    __hip_bfloat16 *ctx;       // [64][512]
    __hip_bfloat16 *AO;        // [1280][512], row = b*20+t
    unsigned *barcnt;          // grid barrier counter (init to 0)
};

#define NBLK 64u

// monotone-counter grid barrier: barrier #e completes when count reaches NBLK*e
__device__ inline void gridbar(unsigned* cnt, unsigned target) {
    __syncthreads();
    if (threadIdx.x == 0) {
        __threadfence();   // release: make this block's stores visible device-wide
        __hip_atomic_fetch_add(cnt, 1u, __ATOMIC_RELAXED, __HIP_MEMORY_SCOPE_AGENT);
        while (__hip_atomic_load(cnt, __ATOMIC_RELAXED, __HIP_MEMORY_SCOPE_AGENT) < target) {}
        __threadfence();   // acquire: invalidate caches before reading others' stores
    }
    __syncthreads();
}

// GRU layer 0 with external (precomputed) GI. Column chunk j0 (16 cols), block=4 waves.
__device__ inline void gru_stage_l0(
    const float* __restrict__ GIt, const __hip_bfloat16* __restrict__ A_gh,
    const __hip_bfloat16* __restrict__ Whh0,
    const float* __restrict__ bih0, const float* __restrict__ bhh0,
    const float* __restrict__ hf_in, float* __restrict__ hf_out,
    __hip_bfloat16* __restrict__ hb_out,
    int j0, int w, int row16, int quad)
{
    int koff = quad * 8;
    const __hip_bfloat16* ah = A_gh + (size_t)(w * 16 + row16) * 512 + koff;
    const __hip_bfloat16* wh0 = Whh0 + (size_t)(j0 + row16) * 512 + koff;
    const __hip_bfloat16* wh1 = wh0 + (size_t)512 * 512;
    const __hip_bfloat16* wh2 = wh1 + (size_t)512 * 512;
    f32x4 gh0 = {0,0,0,0}, gh1 = {0,0,0,0}, gh2 = {0,0,0,0};
    for (int k = 0; k < 512; k += 32) {
        bf16x8 av = *(const bf16x8*)(ah + k);
        gh0 = MFMA(av, *(const bf16x8*)(wh0 + k), gh0);
        gh1 = MFMA(av, *(const bf16x8*)(wh1 + k), gh1);
        gh2 = MFMA(av, *(const bf16x8*)(wh2 + k), gh2);
    }
    int j = j0 + row16;
    float br = bih0[j], bz = bih0[j + 512], bn = bih0[j + 1024];
    float cr = bhh0[j], cz = bhh0[j + 512], cn = bhh0[j + 1024];
#pragma unroll
    for (int r = 0; r < 4; ++r) {
        int b = w * 16 + quad * 4 + r;
        float gir = GIt[(size_t)b * 1536 + j];
        float giz = GIt[(size_t)b * 1536 + j + 512];
        float gin = GIt[(size_t)b * 1536 + j + 1024];
        float rg = sigmf(gir + br + gh0[r] + cr);
        float zg = sigmf(giz + bz + gh1[r] + cz);
        float ng = tanhf(gin + bn + rg * (gh2[r] + cn));
        float hv = (1.f - zg) * ng + zg * hf_in[(size_t)b * 512 + j];
        hf_out[(size_t)b * 512 + j] = hv;
        hb_out[(size_t)b * 512 + j] = __float2bfloat16(hv);
    }
}

// GRU layer computing both GI (from A_gi) and GH (from A_gh) in-register.
__device__ inline void gru_stage_mid(
    const __hip_bfloat16* __restrict__ A_gi, const __hip_bfloat16* __restrict__ A_gh,
    const __hip_bfloat16* __restrict__ Wih_l, const __hip_bfloat16* __restrict__ Whh_l,
    const float* __restrict__ bih_l, const float* __restrict__ bhh_l,
    const float* __restrict__ hf_in, float* __restrict__ hf_out,
    __hip_bfloat16* __restrict__ hb_out,
    int j0, int w, int row16, int quad)
{
    int koff = quad * 8;
    const __hip_bfloat16* ai = A_gi + (size_t)(w * 16 + row16) * 512 + koff;
    const __hip_bfloat16* ah = A_gh + (size_t)(w * 16 + row16) * 512 + koff;
    const __hip_bfloat16* wi0 = Wih_l + (size_t)(j0 + row16) * 512 + koff;
    const __hip_bfloat16* wi1 = wi0 + (size_t)512 * 512;
    const __hip_bfloat16* wi2 = wi1 + (size_t)512 * 512;
    const __hip_bfloat16* wh0 = Whh_l + (size_t)(j0 + row16) * 512 + koff;
    const __hip_bfloat16* wh1 = wh0 + (size_t)512 * 512;
    const __hip_bfloat16* wh2 = wh1 + (size_t)512 * 512;
    f32x4 gi0 = {0,0,0,0}, gi1 = {0,0,0,0}, gi2 = {0,0,0,0};
    f32x4 gh0 = {0,0,0,0}, gh1 = {0,0,0,0}, gh2 = {0,0,0,0};
    for (int k = 0; k < 512; k += 32) {
        bf16x8 av_i = *(const bf16x8*)(ai + k);
        bf16x8 av_h = *(const bf16x8*)(ah + k);
        gi0 = MFMA(av_i, *(const bf16x8*)(wi0 + k), gi0);
        gi1 = MFMA(av_i, *(const bf16x8*)(wi1 + k), gi1);
        gi2 = MFMA(av_i, *(const bf16x8*)(wi2 + k), gi2);
        gh0 = MFMA(av_h, *(const bf16x8*)(wh0 + k), gh0);
        gh1 = MFMA(av_h, *(const bf16x8*)(wh1 + k), gh1);
        gh2 = MFMA(av_h, *(const bf16x8*)(wh2 + k), gh2);
    }
    int j = j0 + row16;
    float br = bih_l[j], bz = bih_l[j + 512], bn = bih_l[j + 1024];
    float cr = bhh_l[j], cz = bhh_l[j + 512], cn = bhh_l[j + 1024];
#pragma unroll
    for (int r = 0; r < 4; ++r) {
        int b = w * 16 + quad * 4 + r;
        float rg = sigmf(gi0[r] + br + gh0[r] + cr);
        float zg = sigmf(gi1[r] + bz + gh1[r] + cz);
        float ng = tanhf(gi2[r] + bn + rg * (gh2[r] + cn));
        float hv = (1.f - zg) * ng + zg * hf_in[(size_t)b * 512 + j];
        hf_out[(size_t)b * 512 + j] = hv;
        hb_out[(size_t)b * 512 + j] = __float2bfloat16(hv);
    }
}

// 64x16 projection tile: acc = A(64x512) @ Bw(16 rows x 512)^T. Caller offsets Bw by j0*512.
__device__ inline f32x4 proj16(const __hip_bfloat16* __restrict__ A,
                               const __hip_bfloat16* __restrict__ Bw,
                               int w, int row16, int quad)
{
    int koff = quad * 8;
    const __hip_bfloat16* ap = A + (size_t)(w * 16 + row16) * 512 + koff;
    const __hip_bfloat16* bp = Bw + (size_t)row16 * 512 + koff;
    f32x4 acc = {0,0,0,0};
    for (int k = 0; k < 512; k += 32)
        acc = MFMA(*(const bf16x8*)(ap + k), *(const bf16x8*)(bp + k), acc);
    return acc;
}

#define HSTATE (3 * 64 * 512)

__global__ void __launch_bounds__(256, 1) recurrence_kernel(RecArgs a) {
    const int tid = threadIdx.x;
    const int blk = blockIdx.x;
    const int w = tid >> 6, lane = tid & 63, row16 = lane & 15, quad = lane >> 4;
    unsigned epoch = 0;

    for (int t = 0; t < TT; ++t) {
        const int cur = t & 1, nxt = cur ^ 1;
        const __hip_bfloat16* hbc = a.hb + cur * HSTATE;
        __hip_bfloat16* hbn = a.hb + nxt * HSTATE;
        const float* hfc = a.hf + cur * HSTATE;
        float* hfn = a.hf + nxt * HSTATE;

        // ---- Stage A: GH0+combine0 (blocks 0..31) | AO for t-1 (blocks 32..63) ----
        if (blk < 32) {
            gru_stage_l0(a.GI0all + (size_t)t * 64 * 1536, hbc, a.whh,
                         a.bih, a.bhh, hfc, hfn, hbn, blk * 16, w, row16, quad);
        } else if (t > 0) {
            int j0 = (blk - 32) * 16;
            f32x4 acc = proj16(a.ctx, a.wo + (size_t)j0 * 512, w, row16, quad);
            int j = j0 + row16;
            float bv = a.bo[j];
#pragma unroll
            for (int r = 0; r < 4; ++r) {
                int b = w * 16 + quad * 4 + r;
                a.AO[(size_t)(b * TT + (t - 1)) * 512 + j] = __float2bfloat16(acc[r] + bv);
            }
        }
        gridbar(a.barcnt, NBLK * ++epoch);

        // ---- Stage B: layer 1 ----
        if (blk < 32)
            gru_stage_mid(hbn, hbc + HSTATE / 3,
                          a.wih + (size_t)1 * 1536 * 512, a.whh + (size_t)1 * 1536 * 512,
                          a.bih + 1536, a.bhh + 1536,
                          hfc + HSTATE / 3, hfn + HSTATE / 3, hbn + HSTATE / 3,
                          blk * 16, w, row16, quad);
        gridbar(a.barcnt, NBLK * ++epoch);

        // ---- Stage C: layer 2 ----
        if (blk < 32)
            gru_stage_mid(hbn + HSTATE / 3, hbc + 2 * (HSTATE / 3),
                          a.wih + (size_t)2 * 1536 * 512, a.whh + (size_t)2 * 1536 * 512,
                          a.bih + 2 * 1536, a.bhh + 2 * 1536,
                          hfc + 2 * (HSTATE / 3), hfn + 2 * (HSTATE / 3),
                          hbn + 2 * (HSTATE / 3),
                          blk * 16, w, row16, quad);
        gridbar(a.barcnt, NBLK * ++epoch);

        // ---- Stage D: q = h2 @ Wq^T + bq ----
        if (blk < 32) {
            int j0 = blk * 16;
            f32x4 acc = proj16(hbn + 2 * (HSTATE / 3), a.wq + (size_t)j0 * 512, w, row16, quad);
            int j = j0 + row16;
            float bv = a.bq[j];
#pragma unroll
            for (int r = 0; r < 4; ++r) {
                int b = w * 16 + quad * 4 + r;
                a.qf[(size_t)b * 512 + j] = acc[r] + bv;
            }
        }
        gridbar(a.barcnt, NBLK * ++epoch);

        // ---- Stage E: attention (512 (b,head) tasks over 256 waves) ----
        {
            int wg = blk * 4 + w;   // 0..255
#pragma unroll
            for (int it = 0; it < 2; ++it) {
                int task = wg * 2 + it;     // 0..511
                int b = task >> 3, h = task & 7;
                const float* qrow = a.qf + (size_t)b * 512 + h * 64;
                const float* kr = a.KV + (size_t)(b * 64 + lane) * 1024 + h * 64;
                float sc = 0.f;
#pragma unroll
                for (int d = 0; d < 64; ++d) sc += qrow[d] * kr[d];
                sc *= 0.125f;
                float m = sc;
                for (int off = 32; off; off >>= 1) m = fmaxf(m, __shfl_xor(m, off, 64));
                float e = __expf(sc - m);
                float s = e;
                for (int off = 32; off; off >>= 1) s += __shfl_xor(s, off, 64);
                float p = e / s;
                float accv = 0.f;
                const float* vb = a.KV + (size_t)(b * 64) * 1024 + 512 + h * 64 + lane;
#pragma unroll
                for (int si = 0; si < 64; ++si) {
                    float ps = __shfl(p, si, 64);
                    accv += ps * vb[(size_t)si * 1024];
                }
                a.ctx[(size_t)b * 512 + h * 64 + lane] = __float2bfloat16(accv);
            }
        }
        gridbar(a.barcnt, NBLK * ++epoch);
    }

    // final AO for t = 19
    if (blk >= 32) {
        int j0 = (blk - 32) * 16;
        f32x4 acc = proj16(a.ctx, a.wo + (size_t)j0 * 512, w, row16, quad);
        int j = j0 + row16;
        float bv = a.bo[j];
#pragma unroll
        for (int r = 0; r < 4; ++r) {
            int b = w * 16 + quad * 4 + r;
            a.AO[(size_t)(b * TT + 19) * 512 + j] = __float2bfloat16(acc[r] + bv);
        }
    }
}

// ---------------- host ----------------

extern "C" void kernel_launch(void* const* d_in, const int* in_sizes, int n_in,
                              void* d_out, int out_size, void* d_ws, size_t ws_size,
                              hipStream_t stream) {
    const float* enc        = (const float*)d_in[0];
    const int*   cap        = (const int*)d_in[1];
    const float* emb_tab    = (const float*)d_in[2];
    const float* w_ih       = (const float*)d_in[3];
    const float* w_hh       = (const float*)d_in[4];
    const float* b_ih       = (const float*)d_in[5];
    const float* b_hh       = (const float*)d_in[6];
    const float* in_proj_w  = (const float*)d_in[7];
    const float* in_proj_b  = (const float*)d_in[8];
    const float* out_proj_w = (const float*)d_in[9];
    const float* out_proj_b = (const float*)d_in[10];
    const float* fc_w       = (const float*)d_in[11];
    const float* fc_b       = (const float*)d_in[12];
    float* out = (float*)d_out;

    char* p = (char*)d_ws;
    auto alloc = [&](size_t bytes) {
        char* r = p;
        p += (bytes + 255) & ~(size_t)255;
        return r;
    };
    __hip_bfloat16* fcw_bf  = (__hip_bfloat16*)alloc((size_t)VV * HH * 2);
    __hip_bfloat16* enc_bf  = (__hip_bfloat16*)alloc((size_t)64 * 64 * 512 * 2);
    __hip_bfloat16* inp_bf  = (__hip_bfloat16*)alloc((size_t)1536 * 512 * 2);
    __hip_bfloat16* wih_bf  = (__hip_bfloat16*)alloc((size_t)3 * 1536 * 512 * 2);
    __hip_bfloat16* whh_bf  = (__hip_bfloat16*)alloc((size_t)3 * 1536 * 512 * 2);
    __hip_bfloat16* wo_bf   = (__hip_bfloat16*)alloc((size_t)512 * 512 * 2);
    __hip_bfloat16* xemb_bf = (__hip_bfloat16*)alloc((size_t)TT * 64 * 512 * 2);
    float* KV     = (float*)alloc((size_t)4096 * 1024 * 4);
    float* GI0all = (float*)alloc((size_t)1280 * 1536 * 4);
    float* hf     = (float*)alloc((size_t)2 * HSTATE * 4);
    __hip_bfloat16* hb = (__hip_bfloat16*)alloc((size_t)2 * HSTATE * 2);
    float* qf     = (float*)alloc((size_t)64 * 512 * 4);
    __hip_bfloat16* ctx_bf = (__hip_bfloat16*)alloc((size_t)64 * 512 * 2);
    __hip_bfloat16* AO     = (__hip_bfloat16*)alloc((size_t)1280 * 512 * 2);
    unsigned* barcnt = (unsigned*)alloc(256);

    auto cvt = [&](const float* src, __hip_bfloat16* dst, size_t n) {
        f2bf_kernel<<<(int)((n + 255) / 256), 256, 0, stream>>>(src, dst, (int)n);
    };
    cvt(fc_w, fcw_bf, (size_t)VV * HH);
    cvt(enc, enc_bf, (size_t)64 * 64 * 512);
    cvt(in_proj_w, inp_bf, (size_t)1536 * 512);
    cvt(w_ih, wih_bf, (size_t)3 * 1536 * 512);
    cvt(w_hh, whh_bf, (size_t)3 * 1536 * 512);
    cvt(out_proj_w, wo_bf, (size_t)512 * 512);
    gather_emb_kernel<<<(TT * 64 * 512) / 256, 256, 0, stream>>>(emb_tab, cap, xemb_bf);
    init_kernel<<<(HSTATE + 255) / 256, 256, 0, stream>>>(hf, hb, HSTATE, barcnt);

    // KV = enc @ [Wk;Wv]^T + [bk;bv]   (4096 x 1024, K=512)
    fastgemm_kernel<<<dim3(32, 8), 256, 0, stream>>>(
        enc_bf, inp_bf + (size_t)512 * 512, in_proj_b + 512, KV, 512, 1024);

    // GI0all = xemb @ Wih0^T  (1280 x 1536, no bias)
    fastgemm_kernel<<<dim3(10, 12), 256, 0, stream>>>(
        xemb_bf, wih_bf, nullptr, GI0all, 512, 1536);

    // recurrence (manual grid barrier, 64 blocks co-resident on 256 CUs)
    RecArgs ra;
    ra.whh = whh_bf; ra.wih = wih_bf; ra.wq = inp_bf; ra.wo = wo_bf;
    ra.bih = b_ih; ra.bhh = b_hh; ra.bq = in_proj_b; ra.bo = out_proj_b;
    ra.GI0all = GI0all; ra.KV = KV;
    ra.hf = hf; ra.hb = hb; ra.qf = qf; ra.ctx = ctx_bf; ra.AO = AO;
    ra.barcnt = barcnt;
    recurrence_kernel<<<dim3(64), dim3(256), 0, stream>>>(ra);

    // logits = AO @ fc_w^T + fc_b  (1280 x 32000) -> d_out (B,T,V)
    fastgemm_kernel<<<dim3(10, 250), 256, 0, stream>>>(
        AO, fcw_bf, fc_b, out, 512, VV);
}